// Round 5
// baseline (170.104 us; speedup 1.0000x reference)
//
#include <hip/hip_runtime.h>

#define HD 512
#define B_MOL 64
#define ASV 24
#define ASU 32
#define AF 133
#define BFD 147
#define NA_SV (B_MOL*ASV)     // 1536
#define NB_SV (2*B_MOL*ASV)   // 3072
#define NA_SU (B_MOL*ASU)     // 2048
#define NB_SU (2*B_MOL*ASU)   // 4096
#define NBT (NB_SV+NB_SU)     // 7168
#define NAT (NA_SV+NA_SU)     // 3584
#define NPAIR (B_MOL*ASV*ASU) // 49152
#define KPAD 192              // 147/133 padded
#define AKP 704               // 192 + 512 combined W_o K

typedef __bf16 bf16x8 __attribute__((ext_vector_type(8)));
typedef float f32x4 __attribute__((ext_vector_type(4)));

__device__ __forceinline__ unsigned short f2bf(float f) {
  unsigned u = __builtin_bit_cast(unsigned, f);
  unsigned r = u + 0x7fffu + ((u >> 16) & 1u);
  return (unsigned short)(r >> 16);
}
__device__ __forceinline__ float bf2f(unsigned short h) {
  unsigned u = ((unsigned)h) << 16;
  return __builtin_bit_cast(float, u);
}

// ============ bf16 MFMA GEMM core: out = epi(A[M][Kp] @ Bt[N][Kp]^T) ========
// BM=128 BN=64 BK=64, 256 threads (4 waves 2x2), 16x16x32 MFMA, dbuf LDS,
// XOR-swizzled LDS via inverse-swizzled global source (rule 21).
// Grid is (M-tiles, N-tiles): x-consecutive blocks share the B-panel so the
// 8 column-blocks reusing one A-panel land on the same XCD (56%8==0).
template<bool ADD_C, bool BIAS, bool RELU, bool RELUB, bool ST_F32, bool ST_BF16, bool ST_B2>
__device__ __forceinline__ void gemm_core(const unsigned short* __restrict__ A,
                                          const unsigned short* __restrict__ Bt,
                                          const unsigned short* __restrict__ CinB,
                                          const float* __restrict__ bias,
                                          float* __restrict__ outF,
                                          unsigned short* __restrict__ outB,
                                          unsigned short* __restrict__ outB2,
                                          int N, int Kp, int bm, int bn) {
  __shared__ unsigned short As[2][128 * 64];
  __shared__ unsigned short Bs[2][64 * 64];
  const int tid = threadIdx.x;
  const int lane = tid & 63;
  const int wave = tid >> 6;
  const int wm = (wave >> 1) * 64;
  const int wn = (wave & 1) * 32;

  f32x4 acc[4][2];
#pragma unroll
  for (int mf = 0; mf < 4; ++mf)
#pragma unroll
    for (int nf = 0; nf < 2; ++nf)
      acc[mf][nf] = f32x4{0.f, 0.f, 0.f, 0.f};

  auto stage = [&](int buf, int k0) {
#pragma unroll
    for (int i = 0; i < 4; ++i) {             // A: 128x64 = 1024 x 16B
      const int s = i * 256 + tid;
      const int row = s >> 3, sl = s & 7;
      const int gk = (sl ^ (row & 7)) << 3;
      const unsigned short* gp = A + (size_t)(bm + row) * Kp + k0 + gk;
      __builtin_amdgcn_global_load_lds(
          (const __attribute__((address_space(1))) void*)gp,
          (__attribute__((address_space(3))) void*)&As[buf][s * 8], 16, 0, 0);
    }
#pragma unroll
    for (int i = 0; i < 2; ++i) {             // B: 64x64 = 512 x 16B
      const int s = i * 256 + tid;
      const int row = s >> 3, sl = s & 7;
      const int gk = (sl ^ (row & 7)) << 3;
      const unsigned short* gp = Bt + (size_t)(bn + row) * Kp + k0 + gk;
      __builtin_amdgcn_global_load_lds(
          (const __attribute__((address_space(1))) void*)gp,
          (__attribute__((address_space(3))) void*)&Bs[buf][s * 8], 16, 0, 0);
    }
  };

  stage(0, 0);
  __syncthreads();
  const int nt = Kp >> 6;
  int cur = 0;
  for (int t = 0; t < nt; ++t) {
    if (t + 1 < nt) stage(cur ^ 1, (t + 1) << 6);
    const int lrow = lane & 15, lgrp = lane >> 4;
#pragma unroll
    for (int kk = 0; kk < 2; ++kk) {
      const int slot = kk * 4 + lgrp;
      bf16x8 af[4], bfr[2];
#pragma unroll
      for (int mf = 0; mf < 4; ++mf) {
        const int row = wm + mf * 16 + lrow;
        af[mf] = *reinterpret_cast<const bf16x8*>(&As[cur][row * 64 + ((slot ^ (row & 7)) << 3)]);
      }
#pragma unroll
      for (int nf = 0; nf < 2; ++nf) {
        const int row = wn + nf * 16 + lrow;
        bfr[nf] = *reinterpret_cast<const bf16x8*>(&Bs[cur][row * 64 + ((slot ^ (row & 7)) << 3)]);
      }
#pragma unroll
      for (int mf = 0; mf < 4; ++mf)
#pragma unroll
        for (int nf = 0; nf < 2; ++nf)
          acc[mf][nf] = __builtin_amdgcn_mfma_f32_16x16x32_bf16(af[mf], bfr[nf], acc[mf][nf], 0, 0, 0);
    }
    __syncthreads();
    cur ^= 1;
  }

  const int lrow = lane & 15, lgrp = lane >> 4;
#pragma unroll
  for (int mf = 0; mf < 4; ++mf)
#pragma unroll
    for (int nf = 0; nf < 2; ++nf)
#pragma unroll
      for (int i = 0; i < 4; ++i) {
        const int row = bm + wm + mf * 16 + lgrp * 4 + i;
        const int col = bn + wn + nf * 16 + lrow;
        const size_t idx = (size_t)row * N + col;
        float v = acc[mf][nf][i];
        if (ADD_C) v += bf2f(CinB[idx]);
        if (BIAS) { if (bias) v += bias[col]; }
        if (RELU) v = fmaxf(v, 0.f);
        if (ST_F32) outF[idx] = v;
        if (ST_B2) outB2[idx] = f2bf(v);
        if (ST_BF16) outB[idx] = RELUB ? f2bf(fmaxf(v, 0.f)) : f2bf(v);
      }
}

template<bool ADD_C, bool BIAS, bool RELU, bool RELUB, bool ST_F32, bool ST_BF16, bool ST_B2>
__launch_bounds__(256)
__global__ void mfma_gemm_k(const unsigned short* __restrict__ A,
                            const unsigned short* __restrict__ Bt,
                            const unsigned short* __restrict__ CinB,
                            const float* __restrict__ bias,
                            float* __restrict__ outF, unsigned short* __restrict__ outB,
                            unsigned short* __restrict__ outB2,
                            int N, int Kp) {
  gemm_core<ADD_C, BIAS, RELU, RELUB, ST_F32, ST_BF16, ST_B2>(
      A, Bt, CinB, bias, outF, outB, outB2, N, Kp, blockIdx.x * 128, blockIdx.y * 64);
}

// grid.z merged U/V attention GEMMs (z=0: U=ah_sv@Wa1_sv + b_a1; z=1: V)
__launch_bounds__(256)
__global__ void mfma_gemm_uv_k(const unsigned short* __restrict__ ahb,
                               const unsigned short* __restrict__ Wt_sv,
                               const unsigned short* __restrict__ Wt_su,
                               const float* __restrict__ b_a1,
                               unsigned short* __restrict__ U_b,
                               unsigned short* __restrict__ V_b) {
  const int z = blockIdx.z;
  const int M = z ? NA_SU : NA_SV;
  if ((int)blockIdx.x * 128 >= M) return;
  const unsigned short* A = z ? ahb + (size_t)NA_SV * HD : ahb;
  const unsigned short* Bt = z ? Wt_su : Wt_sv;
  const float* bias = z ? nullptr : b_a1;
  unsigned short* outB = z ? V_b : U_b;
  gemm_core<false, true, false, false, false, true, false>(
      A, Bt, nullptr, bias, nullptr, outB, nullptr, 1024, HD, blockIdx.x * 128, blockIdx.y * 64);
}

// ============ unified conversions: weights (type 0) + activations (type 1) ==
struct CJobs {
  const float* src[10];
  unsigned short* dst[10];
  int type[10], K[10], N[10], stride[10], colOff[10], region[10], R[10];
};
__global__ void conv_all_k(CJobs J) {
  __shared__ float T[64][65];
  const int j = blockIdx.z;
  const int tid = threadIdx.x;
  if (J.type[j] == 0) {
    const int ktiles = J.region[j] >> 6;
    const int tiles = ktiles * (J.N[j] >> 6);
    const int bx = blockIdx.x;
    if (bx >= tiles) return;
    const int k0 = (bx % ktiles) * 64, n0 = (bx / ktiles) * 64;
    const int r = tid >> 2;
    const int c4 = (tid & 3) * 16;
    const int K = J.K[j], N = J.N[j];
    const float* src = J.src[j];
    const int k = k0 + r;
#pragma unroll
    for (int q = 0; q < 16; ++q)
      T[c4 + q][r] = (k < K) ? src[(size_t)k * N + n0 + c4 + q] : 0.f;
    __syncthreads();
    unsigned short* dst = J.dst[j];
    const int stride = J.stride[j], colOff = J.colOff[j];
#pragma unroll
    for (int q = 0; q < 16; ++q)
      dst[(size_t)(n0 + r) * stride + colOff + k0 + c4 + q] = f2bf(T[r][c4 + q]);
  } else {
    // vectorized pad/convert: one 8-col chunk per thread
    const int id = blockIdx.x * 256 + tid;
    const int nch = KPAD >> 3;                 // 24 chunks per row
    const int total = J.R[j] * nch;
    if (id >= total) return;
    const int r = id / nch;
    const int c8 = (id - r * nch) << 3;
    const int K = J.K[j];
    const float* src = J.src[j] + (size_t)r * K;
    unsigned short o[8];
#pragma unroll
    for (int e = 0; e < 8; ++e) {
      const int k = c8 + e;
      o[e] = (k < K) ? f2bf(src[k]) : (unsigned short)0;
    }
    *reinterpret_cast<uint4*>(&J.dst[j][(size_t)r * J.stride[j] + c8]) =
        *reinterpret_cast<const uint4*>(o);
  }
}

// ============ X[b] = sum_k msg[a2b[b2a[b]][k]] - msg[b2revb[b]] (both graphs)
__global__ void gather_x_k(const unsigned short* __restrict__ msg,
                           const int* __restrict__ a2b_sv, const int* __restrict__ b2a_sv,
                           const int* __restrict__ b2revb_sv,
                           const int* __restrict__ a2b_su, const int* __restrict__ b2a_su,
                           const int* __restrict__ b2revb_su,
                           unsigned short* __restrict__ X) {
  const int idx = blockIdx.x * 256 + threadIdx.x;   // NBT*64 threads
  const int b = idx >> 6, c8 = (idx & 63) << 3;
  if (b >= NBT) return;
  const int* a2b;
  int aL, rev, boff;
  if (b < NB_SV) { a2b = a2b_sv; aL = b2a_sv[b]; rev = b2revb_sv[b]; boff = 0; }
  else {
    const int bl = b - NB_SV;
    a2b = a2b_su; aL = b2a_su[bl]; rev = b2revb_su[bl] + NB_SV; boff = NB_SV;
  }
  float s[8] = {0.f, 0.f, 0.f, 0.f, 0.f, 0.f, 0.f, 0.f};
#pragma unroll
  for (int k = 0; k < 6; ++k) {
    const int bb = a2b[aL * 6 + k] + boff;
    const uint4 v = *reinterpret_cast<const uint4*>(msg + (size_t)bb * HD + c8);
    const unsigned short* p = reinterpret_cast<const unsigned short*>(&v);
#pragma unroll
    for (int e = 0; e < 8; ++e) s[e] += bf2f(p[e]);
  }
  const uint4 rv = *reinterpret_cast<const uint4*>(msg + (size_t)rev * HD + c8);
  const unsigned short* rp = reinterpret_cast<const unsigned short*>(&rv);
  unsigned short o[8];
#pragma unroll
  for (int e = 0; e < 8; ++e) o[e] = f2bf(s[e] - bf2f(rp[e]));
  *reinterpret_cast<uint4*>(X + (size_t)b * HD + c8) = *reinterpret_cast<const uint4*>(o);
}

// ============ final amsg -> a_in[:,192:704] (bf16), both graphs =============
__global__ void gather_sum_k(const unsigned short* __restrict__ msg,
                             const int* __restrict__ a2b_sv, const int* __restrict__ a2b_su,
                             unsigned short* __restrict__ a_in) {
  const int idx = blockIdx.x * 256 + threadIdx.x;   // NAT*64 threads
  const int a = idx >> 6, c8 = (idx & 63) << 3;
  if (a >= NAT) return;
  const int* a2b;
  int aL, boff;
  if (a < NA_SV) { a2b = a2b_sv; aL = a; boff = 0; }
  else { a2b = a2b_su; aL = a - NA_SV; boff = NB_SV; }
  float s[8] = {0.f, 0.f, 0.f, 0.f, 0.f, 0.f, 0.f, 0.f};
#pragma unroll
  for (int k = 0; k < 6; ++k) {
    const int bb = a2b[aL * 6 + k] + boff;
    const uint4 v = *reinterpret_cast<const uint4*>(msg + (size_t)bb * HD + c8);
    const unsigned short* p = reinterpret_cast<const unsigned short*>(&v);
#pragma unroll
    for (int e = 0; e < 8; ++e) s[e] += bf2f(p[e]);
  }
  unsigned short o[8];
#pragma unroll
  for (int e = 0; e < 8; ++e) o[e] = f2bf(s[e]);
  *reinterpret_cast<uint4*>(a_in + (size_t)a * AKP + KPAD + c8) = *reinterpret_cast<const uint4*>(o);
}

// ============ scores: block = (3 U-rows, molecule); V-block in LDS ==========
__launch_bounds__(256)
__global__ void score2_k(const unsigned short* __restrict__ U, const unsigned short* __restrict__ V,
                         const float* __restrict__ w_a2, const float* __restrict__ b_a2,
                         float* __restrict__ scores, float* __restrict__ pmax) {
  __shared__ unsigned short Vs[32 * 1024];   // 64KB
  __shared__ float wred[4];
  const int it = blockIdx.x;                 // 0..7 (3 U-rows each)
  const int b = blockIdx.y;                  // molecule
  const int tid = threadIdx.x;
  const int lane = tid & 63;
  const int wave = tid >> 6;

  // stage V-block (contiguous 64KB) linearly into LDS
  const unsigned short* vbase = V + (size_t)(b * ASU) * 1024;
#pragma unroll
  for (int i = 0; i < 16; ++i) {
    const int c = i * 256 + tid;             // 4096 chunks of 16B
    __builtin_amdgcn_global_load_lds(
        (const __attribute__((address_space(1))) void*)(vbase + c * 8),
        (__attribute__((address_space(3))) void*)&Vs[c * 8], 16, 0, 0);
  }

  // preload 3 U rows (per-lane 16 elems each) + w_a2 frags into regs
  const int i0 = it * 3;
  bf16x8 uf[3][2];
#pragma unroll
  for (int ii = 0; ii < 3; ++ii) {
    const unsigned short* up = U + (size_t)(b * ASV + i0 + ii) * 1024 + lane * 16;
    uf[ii][0] = *reinterpret_cast<const bf16x8*>(up);
    uf[ii][1] = *reinterpret_cast<const bf16x8*>(up + 8);
  }
  float wv[16];
#pragma unroll
  for (int q = 0; q < 4; ++q) {
    const float4 w4 = *reinterpret_cast<const float4*>(w_a2 + lane * 16 + q * 4);
    wv[q * 4] = w4.x; wv[q * 4 + 1] = w4.y; wv[q * 4 + 2] = w4.z; wv[q * 4 + 3] = w4.w;
  }
  const float bias = b_a2[0];
  __syncthreads();

  float m = -1e30f;
#pragma unroll
  for (int ii = 0; ii < 3; ++ii) {
#pragma unroll
    for (int jj = 0; jj < 8; ++jj) {
      const int j = wave * 8 + jj;
      const bf16x8 v0 = *reinterpret_cast<const bf16x8*>(&Vs[j * 1024 + lane * 16]);
      const bf16x8 v1 = *reinterpret_cast<const bf16x8*>(&Vs[j * 1024 + lane * 16 + 8]);
      float s = 0.f;
#pragma unroll
      for (int e = 0; e < 8; ++e) {
        const float x0 = fmaxf((float)uf[ii][0][e] + (float)v0[e], 0.f);
        s = fmaf(x0, wv[e], s);
        const float x1 = fmaxf((float)uf[ii][1][e] + (float)v1[e], 0.f);
        s = fmaf(x1, wv[8 + e], s);
      }
#pragma unroll
      for (int off = 32; off; off >>= 1) s += __shfl_xor(s, off);
      const float sc = s + bias;
      if (lane == 0) scores[(size_t)b * 768 + (i0 + ii) * 32 + j] = sc;
      m = fmaxf(m, sc);
    }
  }
  if (lane == 0) wred[wave] = m;
  __syncthreads();
  if (tid == 0)
    pmax[b * 8 + it] = fmaxf(fmaxf(wred[0], wred[1]), fmaxf(wred[2], wred[3]));
}

// ============ per-molecule: gmax + global sum (redundant) + att means =======
__global__ void mol_combs_k(const float* __restrict__ scores, const float* __restrict__ pmax,
                            const unsigned short* __restrict__ ahb_sv,
                            const unsigned short* __restrict__ ahb_su,
                            float* __restrict__ out) {
  __shared__ float attRow[ASV];
  __shared__ float attCol[ASU];
  __shared__ float red[256];
  const int b = blockIdx.x, tid = threadIdx.x;
  if (tid < ASV) attRow[tid] = 0.f;
  if (tid < ASU) attCol[tid] = 0.f;
  // gmax over 512 per-block maxima
  float m = -1e30f;
  for (int i = tid; i < 512; i += 256) m = fmaxf(m, pmax[i]);
  red[tid] = m; __syncthreads();
  for (int s = 128; s; s >>= 1) {
    if (tid < s) red[tid] = fmaxf(red[tid], red[tid + s]);
    __syncthreads();
  }
  const float gmax = red[0];
  __syncthreads();
  // full sweep: global exp-sum + own-molecule unnormalized att row/col sums
  const int p0 = b * (ASV * ASU), p1 = p0 + ASV * ASU;
  float sum = 0.f;
  for (int p = tid; p < NPAIR; p += 256) {
    const float w = __expf(scores[p] - gmax);
    sum += w;
    if (p >= p0 && p < p1) {
      const int q = p - p0;
      atomicAdd(&attRow[q >> 5], w);
      atomicAdd(&attCol[q & 31], w);
    }
  }
  red[tid] = sum; __syncthreads();
  for (int s = 128; s; s >>= 1) {
    if (tid < s) red[tid] += red[tid + s];
    __syncthreads();
  }
  const float scale = (1.0f / red[0]) * (1.0f / (float)(ASV * ASU));
  // weighted + plain means from bf16 atom states
  for (int c = tid; c < HD; c += 256) {
    float s_att = 0.f, s_pln = 0.f;
    for (int i = 0; i < ASV; ++i) {
      const float v = bf2f(ahb_sv[((size_t)b * ASV + i) * HD + c]);
      s_att = fmaf(attRow[i], v, s_att);
      s_pln += v;
    }
    out[(size_t)b * 2048 + c] = s_pln * (1.0f / ASV);
    out[(size_t)b * 2048 + 512 + c] = s_att * scale;
  }
  for (int c = tid; c < HD; c += 256) {
    float s_att = 0.f, s_pln = 0.f;
    for (int j = 0; j < ASU; ++j) {
      const float v = bf2f(ahb_su[((size_t)b * ASU + j) * HD + c]);
      s_att = fmaf(attCol[j], v, s_att);
      s_pln += v;
    }
    out[(size_t)b * 2048 + 1024 + c] = s_att * scale;
    out[(size_t)b * 2048 + 1536 + c] = s_pln * (1.0f / ASU);
  }
}

extern "C" void kernel_launch(void* const* d_in, const int* in_sizes, int n_in,
                              void* d_out, int out_size, void* d_ws, size_t ws_size,
                              hipStream_t stream) {
  (void)in_sizes; (void)n_in; (void)out_size; (void)ws_size;
  const float* f_atoms_sv = (const float*)d_in[0];
  const float* f_bonds_sv = (const float*)d_in[1];
  const int*   a2b_sv     = (const int*)d_in[2];
  const int*   b2a_sv     = (const int*)d_in[3];
  const int*   b2revb_sv  = (const int*)d_in[4];
  const float* f_atoms_su = (const float*)d_in[5];
  const float* f_bonds_su = (const float*)d_in[6];
  const int*   a2b_su     = (const int*)d_in[7];
  const int*   b2a_su     = (const int*)d_in[8];
  const int*   b2revb_su  = (const int*)d_in[9];
  const float* W_i  = (const float*)d_in[10];
  const float* W_h  = (const float*)d_in[11];
  const float* W_o  = (const float*)d_in[12];
  const float* b_o  = (const float*)d_in[13];
  const float* W_a1 = (const float*)d_in[14];
  const float* b_a1 = (const float*)d_in[15];
  const float* W_a2 = (const float*)d_in[16];
  const float* b_a2 = (const float*)d_in[17];
  float* out = (float*)d_out;

  // -------- workspace carve --------
  float* f = (float*)d_ws;
  float* scores = f;  f += NPAIR;
  float* pmax   = f;  f += 512;

  unsigned short* u = (unsigned short*)f;
  unsigned short* bondsb  = u;  u += (size_t)NBT * KPAD;
  unsigned short* a_in    = u;  u += (size_t)NAT * AKP;
  unsigned short* Wt_i    = u;  u += (size_t)HD * KPAD;
  unsigned short* Wt_h    = u;  u += (size_t)HD * HD;
  unsigned short* Wt_o    = u;  u += (size_t)HD * AKP;
  unsigned short* Wt_a1sv = u;  u += (size_t)1024 * HD;
  unsigned short* Wt_a1su = u;  u += (size_t)1024 * HD;
  unsigned short* msg     = u;  u += (size_t)NBT * HD;
  unsigned short* X       = u;  u += (size_t)NBT * HD;
  unsigned short* ahb     = u;  u += (size_t)NAT * HD;
  unsigned short* inpB    = u;  u += (size_t)NBT * HD;
  // aliases (inpB dead after depth loop; NBT*HD == NA_SV*1024 + NA_SU*1024):
  unsigned short* U_b = inpB;
  unsigned short* V_b = U_b + (size_t)NA_SV * 1024;

  // -------- all conversions in one launch --------
  CJobs cj;
  // weights (type 0)
  cj.type[0]=0; cj.src[0]=W_i;  cj.dst[0]=Wt_i;    cj.K[0]=BFD; cj.N[0]=512;  cj.stride[0]=KPAD; cj.colOff[0]=0;    cj.region[0]=KPAD; cj.R[0]=0;
  cj.type[1]=0; cj.src[1]=W_h;  cj.dst[1]=Wt_h;    cj.K[1]=HD;  cj.N[1]=512;  cj.stride[1]=HD;   cj.colOff[1]=0;    cj.region[1]=HD;   cj.R[1]=0;
  cj.type[2]=0; cj.src[2]=W_o;  cj.dst[2]=Wt_o;    cj.K[2]=AF;  cj.N[2]=512;  cj.stride[2]=AKP;  cj.colOff[2]=0;    cj.region[2]=KPAD; cj.R[2]=0;
  cj.type[3]=0; cj.src[3]=W_o + (size_t)AF*HD; cj.dst[3]=Wt_o; cj.K[3]=HD; cj.N[3]=512; cj.stride[3]=AKP; cj.colOff[3]=KPAD; cj.region[3]=HD; cj.R[3]=0;
  cj.type[4]=0; cj.src[4]=W_a1; cj.dst[4]=Wt_a1sv; cj.K[4]=HD;  cj.N[4]=1024; cj.stride[4]=HD;   cj.colOff[4]=0;    cj.region[4]=HD;   cj.R[4]=0;
  cj.type[5]=0; cj.src[5]=W_a1 + (size_t)HD*1024; cj.dst[5]=Wt_a1su; cj.K[5]=HD; cj.N[5]=1024; cj.stride[5]=HD; cj.colOff[5]=0; cj.region[5]=HD; cj.R[5]=0;
  // activations (type 1) — vectorized, 8-col chunks
  cj.type[6]=1; cj.src[6]=f_bonds_sv; cj.dst[6]=bondsb;                        cj.R[6]=NB_SV; cj.K[6]=BFD; cj.stride[6]=KPAD; cj.N[6]=0; cj.colOff[6]=0; cj.region[6]=0;
  cj.type[7]=1; cj.src[7]=f_bonds_su; cj.dst[7]=bondsb + (size_t)NB_SV*KPAD;   cj.R[7]=NB_SU; cj.K[7]=BFD; cj.stride[7]=KPAD; cj.N[7]=0; cj.colOff[7]=0; cj.region[7]=0;
  cj.type[8]=1; cj.src[8]=f_atoms_sv; cj.dst[8]=a_in;                          cj.R[8]=NA_SV; cj.K[8]=AF;  cj.stride[8]=AKP;  cj.N[8]=0; cj.colOff[8]=0; cj.region[8]=0;
  cj.type[9]=1; cj.src[9]=f_atoms_su; cj.dst[9]=a_in + (size_t)NA_SV*AKP;      cj.R[9]=NA_SU; cj.K[9]=AF;  cj.stride[9]=AKP;  cj.N[9]=0; cj.colOff[9]=0; cj.region[9]=0;
  conv_all_k<<<dim3((NB_SU * (KPAD >> 3) + 255) / 256, 1, 10), 256, 0, stream>>>(cj);

  // -------- merged MPN (both graphs) --------
  // inp (pre-relu, bf16) -> inpB ; msg = relu(inp) bf16
  mfma_gemm_k<false,false,false,true,false,true,true><<<dim3(NBT/128, HD/64), 256, 0, stream>>>(
      bondsb, Wt_i, nullptr, nullptr, nullptr, msg, inpB, HD, KPAD);
  for (int d = 0; d < 2; ++d) {
    gather_x_k<<<NBT * 64 / 256, 256, 0, stream>>>(
        msg, a2b_sv, b2a_sv, b2revb_sv, a2b_su, b2a_su, b2revb_su, X);
    mfma_gemm_k<true,false,true,false,false,true,false><<<dim3(NBT/128, HD/64), 256, 0, stream>>>(
        X, Wt_h, inpB, nullptr, nullptr, msg, nullptr, HD, HD);
  }
  gather_sum_k<<<NAT * 64 / 256, 256, 0, stream>>>(msg, a2b_sv, a2b_su, a_in);
  mfma_gemm_k<false,true,true,false,false,true,false><<<dim3(NAT/128, HD/64), 256, 0, stream>>>(
      a_in, Wt_o, nullptr, b_o, nullptr, ahb, nullptr, HD, AKP);

  // -------- factorized pair attention --------
  mfma_gemm_uv_k<<<dim3(NA_SU/128, 1024/64, 2), 256, 0, stream>>>(
      ahb, Wt_a1sv, Wt_a1su, b_a1, U_b, V_b);
  score2_k<<<dim3(8, 64), 256, 0, stream>>>(U_b, V_b, W_a2, b_a2, scores, pmax);
  mol_combs_k<<<64, 256, 0, stream>>>(scores, pmax, ahb, ahb + (size_t)NA_SV * HD, out);
}

// Round 6
// 122.985 us; speedup vs baseline: 1.3831x; 1.3831x over previous
//
#include <hip/hip_runtime.h>

#define HD 512
#define B_MOL 64
#define ASV 24
#define ASU 32
#define AF 133
#define BFD 147
#define NA_SV (B_MOL*ASV)     // 1536
#define NB_SV (2*B_MOL*ASV)   // 3072
#define NA_SU (B_MOL*ASU)     // 2048
#define NB_SU (2*B_MOL*ASU)   // 4096
#define NBT (NB_SV+NB_SU)     // 7168
#define NAT (NA_SV+NA_SU)     // 3584
#define NPAIR (B_MOL*ASV*ASU) // 49152
#define KPAD 192              // 147/133 padded
#define AKP 704               // 192 + 512 combined W_o K

typedef __bf16 bf16x8 __attribute__((ext_vector_type(8)));
typedef float f32x4 __attribute__((ext_vector_type(4)));

__device__ __forceinline__ unsigned short f2bf(float f) {
  unsigned u = __builtin_bit_cast(unsigned, f);
  unsigned r = u + 0x7fffu + ((u >> 16) & 1u);
  return (unsigned short)(r >> 16);
}
__device__ __forceinline__ float bf2f(unsigned short h) {
  unsigned u = ((unsigned)h) << 16;
  return __builtin_bit_cast(float, u);
}

// ============ bf16 MFMA GEMM core: out = epi(A[M][Kp] @ Bt[N][Kp]^T) ========
// BM=128 BN=64 BK=64, 256 threads (4 waves 2x2), 16x16x32 MFMA, dbuf LDS,
// XOR-swizzled LDS via inverse-swizzled global source (rule 21).
// Grid is (M-tiles, N-tiles): x-consecutive blocks share the B-panel.
template<bool ADD_C, bool BIAS, bool RELU, bool RELUB, bool ST_F32, bool ST_BF16, bool ST_B2>
__device__ __forceinline__ void gemm_core(const unsigned short* __restrict__ A,
                                          const unsigned short* __restrict__ Bt,
                                          const unsigned short* __restrict__ CinB,
                                          const float* __restrict__ bias,
                                          float* __restrict__ outF,
                                          unsigned short* __restrict__ outB,
                                          unsigned short* __restrict__ outB2,
                                          int N, int Kp, int bm, int bn) {
  __shared__ unsigned short As[2][128 * 64];
  __shared__ unsigned short Bs[2][64 * 64];
  const int tid = threadIdx.x;
  const int lane = tid & 63;
  const int wave = tid >> 6;
  const int wm = (wave >> 1) * 64;
  const int wn = (wave & 1) * 32;

  f32x4 acc[4][2];
#pragma unroll
  for (int mf = 0; mf < 4; ++mf)
#pragma unroll
    for (int nf = 0; nf < 2; ++nf)
      acc[mf][nf] = f32x4{0.f, 0.f, 0.f, 0.f};

  auto stage = [&](int buf, int k0) {
#pragma unroll
    for (int i = 0; i < 4; ++i) {             // A: 128x64 = 1024 x 16B
      const int s = i * 256 + tid;
      const int row = s >> 3, sl = s & 7;
      const int gk = (sl ^ (row & 7)) << 3;
      const unsigned short* gp = A + (size_t)(bm + row) * Kp + k0 + gk;
      __builtin_amdgcn_global_load_lds(
          (const __attribute__((address_space(1))) void*)gp,
          (__attribute__((address_space(3))) void*)&As[buf][s * 8], 16, 0, 0);
    }
#pragma unroll
    for (int i = 0; i < 2; ++i) {             // B: 64x64 = 512 x 16B
      const int s = i * 256 + tid;
      const int row = s >> 3, sl = s & 7;
      const int gk = (sl ^ (row & 7)) << 3;
      const unsigned short* gp = Bt + (size_t)(bn + row) * Kp + k0 + gk;
      __builtin_amdgcn_global_load_lds(
          (const __attribute__((address_space(1))) void*)gp,
          (__attribute__((address_space(3))) void*)&Bs[buf][s * 8], 16, 0, 0);
    }
  };

  stage(0, 0);
  __syncthreads();
  const int nt = Kp >> 6;
  int cur = 0;
  for (int t = 0; t < nt; ++t) {
    if (t + 1 < nt) stage(cur ^ 1, (t + 1) << 6);
    const int lrow = lane & 15, lgrp = lane >> 4;
#pragma unroll
    for (int kk = 0; kk < 2; ++kk) {
      const int slot = kk * 4 + lgrp;
      bf16x8 af[4], bfr[2];
#pragma unroll
      for (int mf = 0; mf < 4; ++mf) {
        const int row = wm + mf * 16 + lrow;
        af[mf] = *reinterpret_cast<const bf16x8*>(&As[cur][row * 64 + ((slot ^ (row & 7)) << 3)]);
      }
#pragma unroll
      for (int nf = 0; nf < 2; ++nf) {
        const int row = wn + nf * 16 + lrow;
        bfr[nf] = *reinterpret_cast<const bf16x8*>(&Bs[cur][row * 64 + ((slot ^ (row & 7)) << 3)]);
      }
#pragma unroll
      for (int mf = 0; mf < 4; ++mf)
#pragma unroll
        for (int nf = 0; nf < 2; ++nf)
          acc[mf][nf] = __builtin_amdgcn_mfma_f32_16x16x32_bf16(af[mf], bfr[nf], acc[mf][nf], 0, 0, 0);
    }
    __syncthreads();
    cur ^= 1;
  }

  const int lrow = lane & 15, lgrp = lane >> 4;
#pragma unroll
  for (int mf = 0; mf < 4; ++mf)
#pragma unroll
    for (int nf = 0; nf < 2; ++nf)
#pragma unroll
      for (int i = 0; i < 4; ++i) {
        const int row = bm + wm + mf * 16 + lgrp * 4 + i;
        const int col = bn + wn + nf * 16 + lrow;
        const size_t idx = (size_t)row * N + col;
        float v = acc[mf][nf][i];
        if (ADD_C) v += bf2f(CinB[idx]);
        if (BIAS) { if (bias) v += bias[col]; }
        if (RELU) v = fmaxf(v, 0.f);
        if (ST_F32) outF[idx] = v;
        if (ST_B2) outB2[idx] = f2bf(v);
        if (ST_BF16) outB[idx] = RELUB ? f2bf(fmaxf(v, 0.f)) : f2bf(v);
      }
}

template<bool ADD_C, bool BIAS, bool RELU, bool RELUB, bool ST_F32, bool ST_BF16, bool ST_B2>
__launch_bounds__(256)
__global__ void mfma_gemm_k(const unsigned short* __restrict__ A,
                            const unsigned short* __restrict__ Bt,
                            const unsigned short* __restrict__ CinB,
                            const float* __restrict__ bias,
                            float* __restrict__ outF, unsigned short* __restrict__ outB,
                            unsigned short* __restrict__ outB2,
                            int N, int Kp) {
  gemm_core<ADD_C, BIAS, RELU, RELUB, ST_F32, ST_BF16, ST_B2>(
      A, Bt, CinB, bias, outF, outB, outB2, N, Kp, blockIdx.x * 128, blockIdx.y * 64);
}

// grid.z merged U/V attention GEMMs (z=0: U=ah_sv@Wa1_sv + b_a1; z=1: V)
__launch_bounds__(256)
__global__ void mfma_gemm_uv_k(const unsigned short* __restrict__ ahb,
                               const unsigned short* __restrict__ Wt_sv,
                               const unsigned short* __restrict__ Wt_su,
                               const float* __restrict__ b_a1,
                               unsigned short* __restrict__ U_b,
                               unsigned short* __restrict__ V_b) {
  const int z = blockIdx.z;
  const int M = z ? NA_SU : NA_SV;
  if ((int)blockIdx.x * 128 >= M) return;
  const unsigned short* A = z ? ahb + (size_t)NA_SV * HD : ahb;
  const unsigned short* Bt = z ? Wt_su : Wt_sv;
  const float* bias = z ? nullptr : b_a1;
  unsigned short* outB = z ? V_b : U_b;
  gemm_core<false, true, false, false, false, true, false>(
      A, Bt, nullptr, bias, nullptr, outB, nullptr, 1024, HD, blockIdx.x * 128, blockIdx.y * 64);
}

// ============ unified conversions: weights (type 0) + activations (type 1) ==
struct CJobs {
  const float* src[10];
  unsigned short* dst[10];
  int type[10], K[10], N[10], stride[10], colOff[10], region[10], R[10];
};
__global__ void conv_all_k(CJobs J) {
  __shared__ float T[64][65];
  const int j = blockIdx.z;
  const int tid = threadIdx.x;
  if (J.type[j] == 0) {
    const int ktiles = J.region[j] >> 6;
    const int tiles = ktiles * (J.N[j] >> 6);
    const int bx = blockIdx.x;
    if (bx >= tiles) return;
    const int k0 = (bx % ktiles) * 64, n0 = (bx / ktiles) * 64;
    const int r = tid >> 2;
    const int c4 = (tid & 3) * 16;
    const int K = J.K[j], N = J.N[j];
    const float* src = J.src[j];
    const int k = k0 + r;
#pragma unroll
    for (int q = 0; q < 16; ++q)
      T[c4 + q][r] = (k < K) ? src[(size_t)k * N + n0 + c4 + q] : 0.f;
    __syncthreads();
    unsigned short* dst = J.dst[j];
    const int stride = J.stride[j], colOff = J.colOff[j];
#pragma unroll
    for (int q = 0; q < 16; ++q)
      dst[(size_t)(n0 + r) * stride + colOff + k0 + c4 + q] = f2bf(T[r][c4 + q]);
  } else {
    // vectorized pad/convert: one 8-col chunk per thread
    const int id = blockIdx.x * 256 + tid;
    const int nch = KPAD >> 3;                 // 24 chunks per row
    const int total = J.R[j] * nch;
    if (id >= total) return;
    const int r = id / nch;
    const int c8 = (id - r * nch) << 3;
    const int K = J.K[j];
    const float* src = J.src[j] + (size_t)r * K;
    unsigned short o[8];
#pragma unroll
    for (int e = 0; e < 8; ++e) {
      const int k = c8 + e;
      o[e] = (k < K) ? f2bf(src[k]) : (unsigned short)0;
    }
    *reinterpret_cast<uint4*>(&J.dst[j][(size_t)r * J.stride[j] + c8]) =
        *reinterpret_cast<const uint4*>(o);
  }
}

// ============ X[b] = sum_k msg[a2b[b2a[b]][k]] - msg[b2revb[b]] (both graphs)
__global__ void gather_x_k(const unsigned short* __restrict__ msg,
                           const int* __restrict__ a2b_sv, const int* __restrict__ b2a_sv,
                           const int* __restrict__ b2revb_sv,
                           const int* __restrict__ a2b_su, const int* __restrict__ b2a_su,
                           const int* __restrict__ b2revb_su,
                           unsigned short* __restrict__ X) {
  const int idx = blockIdx.x * 256 + threadIdx.x;   // NBT*64 threads
  const int b = idx >> 6, c8 = (idx & 63) << 3;
  if (b >= NBT) return;
  const int* a2b;
  int aL, rev, boff;
  if (b < NB_SV) { a2b = a2b_sv; aL = b2a_sv[b]; rev = b2revb_sv[b]; boff = 0; }
  else {
    const int bl = b - NB_SV;
    a2b = a2b_su; aL = b2a_su[bl]; rev = b2revb_su[bl] + NB_SV; boff = NB_SV;
  }
  float s[8] = {0.f, 0.f, 0.f, 0.f, 0.f, 0.f, 0.f, 0.f};
#pragma unroll
  for (int k = 0; k < 6; ++k) {
    const int bb = a2b[aL * 6 + k] + boff;
    const uint4 v = *reinterpret_cast<const uint4*>(msg + (size_t)bb * HD + c8);
    const unsigned short* p = reinterpret_cast<const unsigned short*>(&v);
#pragma unroll
    for (int e = 0; e < 8; ++e) s[e] += bf2f(p[e]);
  }
  const uint4 rv = *reinterpret_cast<const uint4*>(msg + (size_t)rev * HD + c8);
  const unsigned short* rp = reinterpret_cast<const unsigned short*>(&rv);
  unsigned short o[8];
#pragma unroll
  for (int e = 0; e < 8; ++e) o[e] = f2bf(s[e] - bf2f(rp[e]));
  *reinterpret_cast<uint4*>(X + (size_t)b * HD + c8) = *reinterpret_cast<const uint4*>(o);
}

// ============ final amsg -> a_in[:,192:704] (bf16), both graphs =============
__global__ void gather_sum_k(const unsigned short* __restrict__ msg,
                             const int* __restrict__ a2b_sv, const int* __restrict__ a2b_su,
                             unsigned short* __restrict__ a_in) {
  const int idx = blockIdx.x * 256 + threadIdx.x;   // NAT*64 threads
  const int a = idx >> 6, c8 = (idx & 63) << 3;
  if (a >= NAT) return;
  const int* a2b;
  int aL, boff;
  if (a < NA_SV) { a2b = a2b_sv; aL = a; boff = 0; }
  else { a2b = a2b_su; aL = a - NA_SV; boff = NB_SV; }
  float s[8] = {0.f, 0.f, 0.f, 0.f, 0.f, 0.f, 0.f, 0.f};
#pragma unroll
  for (int k = 0; k < 6; ++k) {
    const int bb = a2b[aL * 6 + k] + boff;
    const uint4 v = *reinterpret_cast<const uint4*>(msg + (size_t)bb * HD + c8);
    const unsigned short* p = reinterpret_cast<const unsigned short*>(&v);
#pragma unroll
    for (int e = 0; e < 8; ++e) s[e] += bf2f(p[e]);
  }
  unsigned short o[8];
#pragma unroll
  for (int e = 0; e < 8; ++e) o[e] = f2bf(s[e]);
  *reinterpret_cast<uint4*>(a_in + (size_t)a * AKP + KPAD + c8) = *reinterpret_cast<const uint4*>(o);
}

// ============ scores: block = (3 U-rows, molecule); V-block in LDS ==========
// Emits per-block max AND per-block exp-sum (relative to block max) so no
// global score sweep is needed downstream.
__launch_bounds__(256)
__global__ void score2_k(const unsigned short* __restrict__ U, const unsigned short* __restrict__ V,
                         const float* __restrict__ w_a2, const float* __restrict__ b_a2,
                         float* __restrict__ scores, float* __restrict__ pmax,
                         float* __restrict__ psum) {
  __shared__ unsigned short Vs[32 * 1024];   // 64KB
  __shared__ float s_sc[96];
  const int it = blockIdx.x;                 // 0..7 (3 U-rows each)
  const int b = blockIdx.y;                  // molecule
  const int tid = threadIdx.x;
  const int lane = tid & 63;
  const int wave = tid >> 6;

  // stage V-block (contiguous 64KB) linearly into LDS
  const unsigned short* vbase = V + (size_t)(b * ASU) * 1024;
#pragma unroll
  for (int i = 0; i < 16; ++i) {
    const int c = i * 256 + tid;             // 4096 chunks of 16B
    __builtin_amdgcn_global_load_lds(
        (const __attribute__((address_space(1))) void*)(vbase + c * 8),
        (__attribute__((address_space(3))) void*)&Vs[c * 8], 16, 0, 0);
  }

  // preload 3 U rows (per-lane 16 elems each) + w_a2 frags into regs
  const int i0 = it * 3;
  bf16x8 uf[3][2];
#pragma unroll
  for (int ii = 0; ii < 3; ++ii) {
    const unsigned short* up = U + (size_t)(b * ASV + i0 + ii) * 1024 + lane * 16;
    uf[ii][0] = *reinterpret_cast<const bf16x8*>(up);
    uf[ii][1] = *reinterpret_cast<const bf16x8*>(up + 8);
  }
  float wv[16];
#pragma unroll
  for (int q = 0; q < 4; ++q) {
    const float4 w4 = *reinterpret_cast<const float4*>(w_a2 + lane * 16 + q * 4);
    wv[q * 4] = w4.x; wv[q * 4 + 1] = w4.y; wv[q * 4 + 2] = w4.z; wv[q * 4 + 3] = w4.w;
  }
  const float bias = b_a2[0];
  __syncthreads();

#pragma unroll
  for (int ii = 0; ii < 3; ++ii) {
#pragma unroll
    for (int jj = 0; jj < 8; ++jj) {
      const int j = wave * 8 + jj;
      const bf16x8 v0 = *reinterpret_cast<const bf16x8*>(&Vs[j * 1024 + lane * 16]);
      const bf16x8 v1 = *reinterpret_cast<const bf16x8*>(&Vs[j * 1024 + lane * 16 + 8]);
      float s = 0.f;
#pragma unroll
      for (int e = 0; e < 8; ++e) {
        const float x0 = fmaxf((float)uf[ii][0][e] + (float)v0[e], 0.f);
        s = fmaf(x0, wv[e], s);
        const float x1 = fmaxf((float)uf[ii][1][e] + (float)v1[e], 0.f);
        s = fmaf(x1, wv[8 + e], s);
      }
#pragma unroll
      for (int off = 32; off; off >>= 1) s += __shfl_xor(s, off);
      if (lane == 0) {
        const float sc = s + bias;
        scores[(size_t)b * 768 + (i0 + ii) * 32 + j] = sc;
        s_sc[ii * 32 + j] = sc;
      }
    }
  }
  __syncthreads();
  // wave 0: block max + exp-sum over the 96 scores
  if (wave == 0) {
    const float v0 = s_sc[lane];
    const float v1 = (lane < 32) ? s_sc[64 + lane] : -1e30f;
    float mx = fmaxf(v0, v1);
#pragma unroll
    for (int off = 32; off; off >>= 1) mx = fmaxf(mx, __shfl_xor(mx, off));
    float e = __expf(v0 - mx) + ((lane < 32) ? __expf(v1 - mx) : 0.f);
#pragma unroll
    for (int off = 32; off; off >>= 1) e += __shfl_xor(e, off);
    if (lane == 0) { pmax[b * 8 + it] = mx; psum[b * 8 + it] = e; }
  }
}

// ============ per-molecule: softmax finalize (512 blocks' stats) + means ====
__global__ void mol_combs_k(const float* __restrict__ scores, const float* __restrict__ pmax,
                            const float* __restrict__ psum,
                            const unsigned short* __restrict__ ahb_sv,
                            const unsigned short* __restrict__ ahb_su,
                            float* __restrict__ out) {
  __shared__ float attRow[ASV];
  __shared__ float attCol[ASU];
  __shared__ float red[256];
  const int b = blockIdx.x, tid = threadIdx.x;
  if (tid < ASV) attRow[tid] = 0.f;
  if (tid < ASU) attCol[tid] = 0.f;
  // gmax over 512 per-block maxima
  float m = -1e30f;
  for (int i = tid; i < 512; i += 256) m = fmaxf(m, pmax[i]);
  red[tid] = m; __syncthreads();
  for (int s = 128; s; s >>= 1) {
    if (tid < s) red[tid] = fmaxf(red[tid], red[tid + s]);
    __syncthreads();
  }
  const float gmax = red[0];
  __syncthreads();
  // total = sum_i psum[i] * exp(pmax[i] - gmax)
  float sum = 0.f;
  for (int i = tid; i < 512; i += 256) sum += psum[i] * __expf(pmax[i] - gmax);
  red[tid] = sum; __syncthreads();
  for (int s = 128; s; s >>= 1) {
    if (tid < s) red[tid] += red[tid + s];
    __syncthreads();
  }
  const float inv = 1.0f / red[0];
  // own-molecule att row/col sums (768 scores, 3 iters)
  for (int q = tid; q < ASV * ASU; q += 256) {
    const float w = __expf(scores[(size_t)b * (ASV * ASU) + q] - gmax) * inv;
    atomicAdd(&attRow[q >> 5], w);
    atomicAdd(&attCol[q & 31], w);
  }
  __syncthreads();
  const float invP = 1.0f / (float)(ASV * ASU);
  // weighted + plain means from bf16 atom states
  for (int c = tid; c < HD; c += 256) {
    float s_att = 0.f, s_pln = 0.f;
    for (int i = 0; i < ASV; ++i) {
      const float v = bf2f(ahb_sv[((size_t)b * ASV + i) * HD + c]);
      s_att = fmaf(attRow[i], v, s_att);
      s_pln += v;
    }
    out[(size_t)b * 2048 + c] = s_pln * (1.0f / ASV);
    out[(size_t)b * 2048 + 512 + c] = s_att * invP;
  }
  for (int c = tid; c < HD; c += 256) {
    float s_att = 0.f, s_pln = 0.f;
    for (int j = 0; j < ASU; ++j) {
      const float v = bf2f(ahb_su[((size_t)b * ASU + j) * HD + c]);
      s_att = fmaf(attCol[j], v, s_att);
      s_pln += v;
    }
    out[(size_t)b * 2048 + 1024 + c] = s_att * invP;
    out[(size_t)b * 2048 + 1536 + c] = s_pln * (1.0f / ASU);
  }
}

extern "C" void kernel_launch(void* const* d_in, const int* in_sizes, int n_in,
                              void* d_out, int out_size, void* d_ws, size_t ws_size,
                              hipStream_t stream) {
  (void)in_sizes; (void)n_in; (void)out_size; (void)ws_size;
  const float* f_atoms_sv = (const float*)d_in[0];
  const float* f_bonds_sv = (const float*)d_in[1];
  const int*   a2b_sv     = (const int*)d_in[2];
  const int*   b2a_sv     = (const int*)d_in[3];
  const int*   b2revb_sv  = (const int*)d_in[4];
  const float* f_atoms_su = (const float*)d_in[5];
  const float* f_bonds_su = (const float*)d_in[6];
  const int*   a2b_su     = (const int*)d_in[7];
  const int*   b2a_su     = (const int*)d_in[8];
  const int*   b2revb_su  = (const int*)d_in[9];
  const float* W_i  = (const float*)d_in[10];
  const float* W_h  = (const float*)d_in[11];
  const float* W_o  = (const float*)d_in[12];
  const float* b_o  = (const float*)d_in[13];
  const float* W_a1 = (const float*)d_in[14];
  const float* b_a1 = (const float*)d_in[15];
  const float* W_a2 = (const float*)d_in[16];
  const float* b_a2 = (const float*)d_in[17];
  float* out = (float*)d_out;

  // -------- workspace carve --------
  float* f = (float*)d_ws;
  float* scores = f;  f += NPAIR;
  float* pmax   = f;  f += 512;
  float* psum   = f;  f += 512;

  unsigned short* u = (unsigned short*)f;
  unsigned short* bondsb  = u;  u += (size_t)NBT * KPAD;
  unsigned short* a_in    = u;  u += (size_t)NAT * AKP;
  unsigned short* Wt_i    = u;  u += (size_t)HD * KPAD;
  unsigned short* Wt_h    = u;  u += (size_t)HD * HD;
  unsigned short* Wt_o    = u;  u += (size_t)HD * AKP;
  unsigned short* Wt_a1sv = u;  u += (size_t)1024 * HD;
  unsigned short* Wt_a1su = u;  u += (size_t)1024 * HD;
  unsigned short* msg     = u;  u += (size_t)NBT * HD;
  unsigned short* X       = u;  u += (size_t)NBT * HD;
  unsigned short* ahb     = u;  u += (size_t)NAT * HD;
  unsigned short* inpB    = u;  u += (size_t)NBT * HD;
  // aliases (inpB dead after depth loop; NBT*HD == NA_SV*1024 + NA_SU*1024):
  unsigned short* U_b = inpB;
  unsigned short* V_b = U_b + (size_t)NA_SV * 1024;

  // -------- all conversions in one launch --------
  CJobs cj;
  // weights (type 0)
  cj.type[0]=0; cj.src[0]=W_i;  cj.dst[0]=Wt_i;    cj.K[0]=BFD; cj.N[0]=512;  cj.stride[0]=KPAD; cj.colOff[0]=0;    cj.region[0]=KPAD; cj.R[0]=0;
  cj.type[1]=0; cj.src[1]=W_h;  cj.dst[1]=Wt_h;    cj.K[1]=HD;  cj.N[1]=512;  cj.stride[1]=HD;   cj.colOff[1]=0;    cj.region[1]=HD;   cj.R[1]=0;
  cj.type[2]=0; cj.src[2]=W_o;  cj.dst[2]=Wt_o;    cj.K[2]=AF;  cj.N[2]=512;  cj.stride[2]=AKP;  cj.colOff[2]=0;    cj.region[2]=KPAD; cj.R[2]=0;
  cj.type[3]=0; cj.src[3]=W_o + (size_t)AF*HD; cj.dst[3]=Wt_o; cj.K[3]=HD; cj.N[3]=512; cj.stride[3]=AKP; cj.colOff[3]=KPAD; cj.region[3]=HD; cj.R[3]=0;
  cj.type[4]=0; cj.src[4]=W_a1; cj.dst[4]=Wt_a1sv; cj.K[4]=HD;  cj.N[4]=1024; cj.stride[4]=HD;   cj.colOff[4]=0;    cj.region[4]=HD;   cj.R[4]=0;
  cj.type[5]=0; cj.src[5]=W_a1 + (size_t)HD*1024; cj.dst[5]=Wt_a1su; cj.K[5]=HD; cj.N[5]=1024; cj.stride[5]=HD; cj.colOff[5]=0; cj.region[5]=HD; cj.R[5]=0;
  // activations (type 1) — vectorized, 8-col chunks
  cj.type[6]=1; cj.src[6]=f_bonds_sv; cj.dst[6]=bondsb;                        cj.R[6]=NB_SV; cj.K[6]=BFD; cj.stride[6]=KPAD; cj.N[6]=0; cj.colOff[6]=0; cj.region[6]=0;
  cj.type[7]=1; cj.src[7]=f_bonds_su; cj.dst[7]=bondsb + (size_t)NB_SV*KPAD;   cj.R[7]=NB_SU; cj.K[7]=BFD; cj.stride[7]=KPAD; cj.N[7]=0; cj.colOff[7]=0; cj.region[7]=0;
  cj.type[8]=1; cj.src[8]=f_atoms_sv; cj.dst[8]=a_in;                          cj.R[8]=NA_SV; cj.K[8]=AF;  cj.stride[8]=AKP;  cj.N[8]=0; cj.colOff[8]=0; cj.region[8]=0;
  cj.type[9]=1; cj.src[9]=f_atoms_su; cj.dst[9]=a_in + (size_t)NA_SV*AKP;      cj.R[9]=NA_SU; cj.K[9]=AF;  cj.stride[9]=AKP;  cj.N[9]=0; cj.colOff[9]=0; cj.region[9]=0;
  conv_all_k<<<dim3((NB_SU * (KPAD >> 3) + 255) / 256, 1, 10), 256, 0, stream>>>(cj);

  // -------- merged MPN (both graphs) --------
  // inp (pre-relu, bf16) -> inpB ; msg = relu(inp) bf16
  mfma_gemm_k<false,false,false,true,false,true,true><<<dim3(NBT/128, HD/64), 256, 0, stream>>>(
      bondsb, Wt_i, nullptr, nullptr, nullptr, msg, inpB, HD, KPAD);
  for (int d = 0; d < 2; ++d) {
    gather_x_k<<<NBT * 64 / 256, 256, 0, stream>>>(
        msg, a2b_sv, b2a_sv, b2revb_sv, a2b_su, b2a_su, b2revb_su, X);
    mfma_gemm_k<true,false,true,false,false,true,false><<<dim3(NBT/128, HD/64), 256, 0, stream>>>(
        X, Wt_h, inpB, nullptr, nullptr, msg, nullptr, HD, HD);
  }
  gather_sum_k<<<NAT * 64 / 256, 256, 0, stream>>>(msg, a2b_sv, a2b_su, a_in);
  mfma_gemm_k<false,true,true,false,false,true,false><<<dim3(NAT/128, HD/64), 256, 0, stream>>>(
      a_in, Wt_o, nullptr, b_o, nullptr, ahb, nullptr, HD, AKP);

  // -------- factorized pair attention --------
  mfma_gemm_uv_k<<<dim3(NA_SU/128, 1024/64, 2), 256, 0, stream>>>(
      ahb, Wt_a1sv, Wt_a1su, b_a1, U_b, V_b);
  score2_k<<<dim3(8, 64), 256, 0, stream>>>(U_b, V_b, W_a2, b_a2, scores, pmax, psum);
  mol_combs_k<<<64, 256, 0, stream>>>(scores, pmax, psum, ahb, ahb + (size_t)NA_SV * HD, out);
}